// Round 14
// baseline (319.041 us; speedup 1.0000x reference)
//
#include <hip/hip_runtime.h>
#include <math.h>

// Round 25: PER-KERNEL ATTRIBUTION. R24 measured: each 4-kernel pipeline =
// 64.5us, cold==warm, partition-invariant -> cost is inside the kernels
// (~16us each vs 2-5us modeled). All structural theories falsified.
// This round: 4 diagnostic kernels, each looping its phase body 4x over
// scratch -> each dispatch ~50-64us -> lands in rocprof top-5 WITH counters
// (dur/4 = per-iter time; VALUBusy/FETCH/Occ diagnose the class).
// Readout: kD_hist big -> device-atomic-bound; kD_main big -> latency chain;
// all equal -> generic floor (roofline next); kD_scan big -> lookback spins.
// Real pipeline (after diagnostics) is byte-identical R23 -> absmax 0.

#define NB (1 << 18)             // linear time buckets, lambda = 1
#define BLK 256
#define M40 ((1ull << 40) - 1)

#define STORE_F32_A(p, v) __hip_atomic_store((p), (v), __ATOMIC_RELAXED, __HIP_MEMORY_SCOPE_AGENT)
#define STORE_U64_A(p, v) __hip_atomic_store((unsigned long long*)(p), (v), __ATOMIC_RELAXED, __HIP_MEMORY_SCOPE_AGENT)
#define LOAD_U64_A(p) __hip_atomic_load((const unsigned long long*)(p), __ATOMIC_RELAXED, __HIP_MEMORY_SCOPE_AGENT)
#define LOAD_F32_A(p) __hip_atomic_load((const float*)(p), __ATOMIC_RELAXED, __HIP_MEMORY_SCOPE_AGENT)
#define FADD_U32_A(p, v) __hip_atomic_fetch_add((p), (v), __ATOMIC_RELAXED, __HIP_MEMORY_SCOPE_AGENT)

__device__ __forceinline__ int lin_bucket(float t) {
  int b = (int)(t * 256.0f);     // exact (pow2 scale): strictly monotone
  if (b < 0) b = 0;
  if (b > NB - 1) b = NB - 1;
  return b;
}

// ================= phase bodies (shared by real + diagnostic) =============
__device__ __forceinline__ void hist_body(
    const float2* __restrict__ yt0, const float* __restrict__ yp0,
    const int* __restrict__ Hj, int n, int m, int tot, int i,
    unsigned long long* __restrict__ rec, unsigned* __restrict__ seq,
    unsigned* __restrict__ bitmap) {
  if (i < n) {
    float2 te = yt0[i];
    float e = expf(yp0[i]);
    int b = lin_bucket(te.x);
    unsigned long long qe = (unsigned long long)(e * 16777216.0f + 0.5f);
    if (qe > (1ull << 32)) qe = (1ull << 32);
    unsigned long long ret = atomicAdd(&rec[b], (1ull << 40) | qe);
    seq[i] = (unsigned)(ret >> 40);
  }
  for (int j = i; j < m; j += tot) {
    int h = Hj[j];
    atomicOr(&bitmap[h >> 5], 1u << (h & 31));
  }
}

__device__ __forceinline__ void scan_body(
    const unsigned long long* __restrict__ rec,
    unsigned long long* __restrict__ pub,
    unsigned long long* __restrict__ Epack,
    unsigned* su, float* sf, int t, int g) {
  unsigned cK[4]; float fK[4];
  unsigned runc = 0u; float runf = 0.f;
  #pragma unroll
  for (int k = 0; k < 4; ++k) {
    int b = NB - 1 - (g * 1024 + t * 4 + k);
    unsigned long long v = rec[b];
    cK[k] = (unsigned)(v >> 40);
    fK[k] = (float)((double)(v & M40) * (1.0 / 16777216.0));
    runc += cK[k]; runf += fK[k];
  }
  su[t] = runc; sf[t] = runf;
  __syncthreads();
  for (int off2 = 1; off2 < BLK; off2 <<= 1) {
    unsigned uc = (t >= off2) ? su[t - off2] : 0u;
    float    uf = (t >= off2) ? sf[t - off2] : 0.f;
    __syncthreads();
    su[t] += uc; sf[t] += uf;
    __syncthreads();
  }
  if (t == BLK - 1)
    STORE_U64_A(&pub[g], (1ull << 63) |
                ((unsigned long long)(su[t] & 0x7FFFFFFFu) << 32) |
                (unsigned long long)__float_as_uint(sf[t]));
  unsigned thrC = (t > 0) ? su[t - 1] : 0u;
  float    thrF = (t > 0) ? sf[t - 1] : 0.f;
  __syncthreads();

  unsigned pc = 0u; float pf = 0.f;
  for (int j = t; j < g; j += BLK) {
    unsigned long long v;
    int guard = 0;
    while (!(((v = LOAD_U64_A(&pub[j])) >> 63) & 1ull)) {
      __builtin_amdgcn_s_sleep(1);
      if (++guard > 5000000) break;
    }
    pc += (unsigned)((v >> 32) & 0x7FFFFFFFu);
    pf += __uint_as_float((unsigned)v);
  }
  su[t] = pc; sf[t] = pf;
  __syncthreads();
  for (int s = BLK / 2; s > 0; s >>= 1) {
    if (t < s) { su[t] += su[t + s]; sf[t] += sf[t + s]; }
    __syncthreads();
  }
  const unsigned baseC = su[0]; const float baseF = sf[0];
  __syncthreads();

  unsigned preC = 0u; float preF = 0.f;
  #pragma unroll
  for (int k = 0; k < 4; ++k) {
    int b = NB - 1 - (g * 1024 + t * 4 + k);
    unsigned sfxC = baseC + thrC + preC;
    float    sfxF = baseF + thrF + preF;
    Epack[b] = ((unsigned long long)__float_as_uint(sfxF) << 32) | sfxC;
    preC += cK[k]; preF += fK[k];
  }
}

__device__ __forceinline__ void scatter_body(
    const float2* __restrict__ yt0, const float* __restrict__ yp0, int n, int i,
    const unsigned* __restrict__ seq,
    const unsigned long long* __restrict__ Epack,
    uint2* __restrict__ skey2, unsigned* __restrict__ sidx) {
  if (i >= n) return;
  float2 te = yt0[i];
  unsigned key = __float_as_uint(te.x);
  int b = lin_bucket(te.x);
  const unsigned* E32 = (const unsigned*)Epack;
  unsigned start = E32[2u * (unsigned)b];
  unsigned end = (b > 0) ? E32[2u * (unsigned)(b - 1)] : (unsigned)n;
  if (end - start < 2u) return;
  float e = expf(yp0[i]);
  unsigned pos = start + seq[i];
  uint2 v; v.x = key; v.y = __float_as_uint(e);
  skey2[pos] = v;
  sidx[pos] = (unsigned)i;
}

__device__ __forceinline__ void main_body(
    const float2* __restrict__ yt0, const float* __restrict__ yp0,
    const float* __restrict__ yp1, const int* __restrict__ Hj,
    const float* __restrict__ lv, int n, int m, int i, int t, int gridN,
    const unsigned* __restrict__ bitmap,
    const unsigned long long* __restrict__ Epack,
    const uint2* __restrict__ skey2, const unsigned* __restrict__ sidx,
    float* __restrict__ xh, double* __restrict__ accum,
    unsigned* __restrict__ doneCnt, float* __restrict__ out,
    double* sd, float* wt, int* lastFlag) {
  double contrib = 0.0;
  if (i < n) {
    float2 te = yt0[i];
    unsigned key = __float_as_uint(te.x);
    bool evb = (te.y != 0.f);
    float e = expf(yp0[i]);
    int b = lin_bucket(te.x);
    unsigned long long ep = Epack[b];
    unsigned start = (unsigned)ep;
    float cross = __uint_as_float((unsigned)(ep >> 32));
    unsigned end = (b > 0) ? ((const unsigned*)Epack)[2u * (unsigned)(b - 1)]
                           : (unsigned)n;
    if (end > (unsigned)n) end = (unsigned)n;
    if (start > end) start = end;
    float wsum = 0.f;
    unsigned wcnt = 0u;
    if (end - start > 1u) {
      for (unsigned q = start; q < end; ++q) {
        uint2 v = skey2[q];
        if (v.x > key) { wsum += __uint_as_float(v.y); wcnt++; }
        else if (v.x == key && sidx[q] < (unsigned)i) {
          wsum += __uint_as_float(v.y); wcnt++;
        }
      }
    }
    float denom = cross + wsum + e;
    int rank = (int)(start + wcnt);
    if (evb) contrib = (double)logf(denom / e);
    if ((bitmap[rank >> 5] >> (rank & 31)) & 1u) {
      int lo = 0, hi = m;
      while (lo < hi) { int mid = (lo + hi) >> 1; if (Hj[mid] < rank) lo = mid + 1; else hi = mid; }
      if (lo < m && Hj[lo] == rank) {
        float xb1 = yp1[i];
        for (int j = lo; j < m && Hj[j] == rank; ++j) STORE_F32_A(&xh[j], xb1);
      }
    }
  }
  sd[t] = contrib;
  __syncthreads();
  for (int s = 128; s > 0; s >>= 1) { if (t < s) sd[t] += sd[t + s]; __syncthreads(); }
  if (t == 0) {
    double old = atomicAdd(accum, sd[0]);
    unsigned long long ob = __double_as_longlong(old);
    asm volatile("" :: "v"(ob));
    unsigned r = FADD_U32_A(doneCnt, 1u);
    *lastFlag = (r == (unsigned)gridN - 1u) ? 1 : 0;
  }
  __syncthreads();
  if (*lastFlag == 0) return;

  {
    int lane = t & 63;
    int w = t >> 6;
    double acc = 0.0;
    float carry = 0.f;
    int passes = (m + 2047) / 2048;
    for (int pss = passes - 1; pss >= 0; --pss) {
      int base = pss * 2048 + t * 8;
      float x[8], eb[8];
      float c = 0.f;
      #pragma unroll
      for (int k = 0; k < 8; ++k) {
        int j = base + k;
        x[k] = (j < m) ? LOAD_F32_A(&xh[j]) : 0.f;
        eb[k] = (j < m) ? expf(-x[k]) : 0.f;
        c += eb[k];
      }
      float s = c;
      #pragma unroll
      for (int d = 1; d < 64; d <<= 1) {
        float o = __shfl_down(s, d, 64);
        if (lane + d < 64) s += o;
      }
      float wtot = __shfl(s, 0, 64);
      if (lane == 0) wt[w] = wtot;
      __syncthreads();
      float after = 0.f, ptot = 0.f;
      #pragma unroll
      for (int w2 = 0; w2 < 4; ++w2) { ptot += wt[w2]; if (w2 > w) after += wt[w2]; }
      float S = (s - c) + after + carry;
      #pragma unroll
      for (int k = 7; k >= 0; --k) {
        int j = base + k;
        S += eb[k];
        if (j < m) acc += (double)(expf(x[k]) * S);
      }
      __syncthreads();
      carry += ptot;
    }
    sd[t] = acc;
    __syncthreads();
    for (int s2 = 128; s2 > 0; s2 >>= 1) { if (t < s2) sd[t] += sd[t + s2]; __syncthreads(); }
    if (t == 0) {
      double T = (double)m * (double)(m + 1) * 0.5;
      double cost2 = T - sd[0];
      float lv0 = lv[0], lv1 = lv[1];
      float prec1 = fminf(expf(-lv1), 1.0f);
      double av = __longlong_as_double((long long)LOAD_U64_A(accum));
      double loss = av + (double)n * (double)lv0 + (double)prec1 * cost2 + (double)lv1;
      out[0] = (float)loss;
    }
  }
}

// ================= real kernels (byte-identical behavior to R23) ==========
__global__ void __launch_bounds__(BLK, 4)
k_hist(const float2* yt0, const float* yp0, const int* Hj, int n, int m,
       int tot, unsigned long long* rec, unsigned* seq, unsigned* bitmap) {
  int i = blockIdx.x * BLK + threadIdx.x;
  hist_body(yt0, yp0, Hj, n, m, tot, i, rec, seq, bitmap);
}

__global__ void __launch_bounds__(BLK, 4)
k_scan(const unsigned long long* rec, unsigned long long* pub,
       unsigned long long* Epack) {
  __shared__ unsigned su[BLK];
  __shared__ float    sf[BLK];
  scan_body(rec, pub, Epack, su, sf, threadIdx.x, blockIdx.x);
}

__global__ void __launch_bounds__(BLK, 4)
k_scatter(const float2* yt0, const float* yp0, int n, const unsigned* seq,
          const unsigned long long* Epack, uint2* skey2, unsigned* sidx) {
  int i = blockIdx.x * BLK + threadIdx.x;
  scatter_body(yt0, yp0, n, i, seq, Epack, skey2, sidx);
}

__global__ void __launch_bounds__(BLK, 4)
k_main(const float2* yt0, const float* yp0, const float* yp1, const int* Hj,
       const float* lv, int n, int m, const unsigned* bitmap,
       const unsigned long long* Epack, const uint2* skey2,
       const unsigned* sidx, float* xh, double* accum, unsigned* doneCnt,
       float* out) {
  __shared__ double sd[BLK];
  __shared__ float  wt[4];
  __shared__ int    lastFlag;
  int i = blockIdx.x * BLK + threadIdx.x;
  main_body(yt0, yp0, yp1, Hj, lv, n, m, i, threadIdx.x, gridDim.x,
            bitmap, Epack, skey2, sidx, xh, accum, doneCnt, out,
            sd, wt, &lastFlag);
}

// ================= diagnostic kernels (4x body, scratch) ==================
__global__ void __launch_bounds__(BLK, 4)
kD_hist(const float2* yt0, const float* yp0, const int* Hj, int n, int m,
        int tot, unsigned long long* recD, unsigned* seq, unsigned* bitmap) {
  int i = blockIdx.x * BLK + threadIdx.x;
  #pragma unroll 1
  for (int r = 0; r < 4; ++r) {
    hist_body(yt0, yp0, Hj, n, m, tot, i, recD + (size_t)r * NB, seq, bitmap);
    asm volatile("" ::: "memory");
  }
}

__global__ void __launch_bounds__(BLK, 4)
kD_scan(const unsigned long long* recD, unsigned long long* pubD,
        unsigned long long* Epack) {
  __shared__ unsigned su[BLK];
  __shared__ float    sf[BLK];
  #pragma unroll 1
  for (int r = 0; r < 4; ++r) {
    scan_body(recD + (size_t)r * NB, pubD + (size_t)r * 256, Epack,
              su, sf, threadIdx.x, blockIdx.x);
    __syncthreads();
    asm volatile("" ::: "memory");
  }
}

__global__ void __launch_bounds__(BLK, 4)
kD_scatter(const float2* yt0, const float* yp0, int n, const unsigned* seq,
           const unsigned long long* Epack, uint2* skey2, unsigned* sidx) {
  int i = blockIdx.x * BLK + threadIdx.x;
  #pragma unroll 1
  for (int r = 0; r < 4; ++r) {
    scatter_body(yt0, yp0, n, i, seq, Epack, skey2, sidx);
    asm volatile("" ::: "memory");
  }
}

__global__ void __launch_bounds__(BLK, 4)
kD_main(const float2* yt0, const float* yp0, const float* yp1, const int* Hj,
        const float* lv, int n, int m, const unsigned* bitmap,
        const unsigned long long* Epack, const uint2* skey2,
        const unsigned* sidx, float* xh, double* accumD, unsigned* doneCntD,
        float* out) {
  __shared__ double sd[BLK];
  __shared__ float  wt[4];
  __shared__ int    lastFlag;
  int i = blockIdx.x * BLK + threadIdx.x;
  #pragma unroll 1
  for (int r = 0; r < 4; ++r) {
    main_body(yt0, yp0, yp1, Hj, lv, n, m, i, threadIdx.x, gridDim.x,
              bitmap, Epack, skey2, sidx, xh, accumD + (size_t)r * 16,
              doneCntD + (size_t)r * 32, out, sd, wt, &lastFlag);
    __syncthreads();
    asm volatile("" ::: "memory");
  }
}

extern "C" void kernel_launch(void* const* d_in, const int* in_sizes, int n_in,
                              void* d_out, int out_size, void* d_ws, size_t ws_size,
                              hipStream_t stream) {
  (void)n_in; (void)out_size;
  const float2* yt0 = (const float2*)d_in[0];
  const float*  yp0 = (const float*)d_in[2];
  const float*  yp1 = (const float*)d_in[3];
  const int*    Hj  = (const int*)d_in[4];
  const float*  lv  = (const float*)d_in[5];
  int n = in_sizes[0] / 2;   // y_true0 is [N,2]
  int m = in_sizes[4];

  char* ws = (char*)d_ws;
  size_t off = 0;
  auto alloc = [&](size_t bytes) -> void* {
    void* p = ws + off;
    off += (bytes + 255) & ~(size_t)255;
    return p;
  };
  size_t nbm = ((size_t)(n + 31) / 32) * 4;                        // 32 KB

  // ---- real zero region ----
  double*   accum   = (double*)alloc(128);
  unsigned* doneCnt = (unsigned*)alloc(128);
  unsigned* bitmap  = (unsigned*)alloc(nbm);
  unsigned long long* pub = (unsigned long long*)alloc((NB / 1024) * 8);
  unsigned long long* rec = (unsigned long long*)alloc((size_t)NB * 8);  // 2MB
  size_t zReal = off;
  // ---- diagnostic zero region ----
  double*   accumD   = (double*)alloc(4 * 16 * 8);
  unsigned* doneCntD = (unsigned*)alloc(4 * 32 * 4);
  unsigned* bitmapD  = (unsigned*)alloc(nbm);
  unsigned long long* pubD = (unsigned long long*)alloc(4 * 256 * 8);
  unsigned long long* recD = (unsigned long long*)alloc((size_t)4 * NB * 8); // 8MB
  size_t zAll = off;

  // ---- real non-zero ----
  unsigned long long* Epack = (unsigned long long*)alloc((size_t)NB * 8);
  unsigned* seq   = (unsigned*)alloc((size_t)n * 4);
  uint2*    skey2 = (uint2*)alloc((size_t)n * 8);
  unsigned* sidx  = (unsigned*)alloc((size_t)n * 4);
  float*    xh    = (float*)alloc((size_t)m * 4);
  size_t offReal = off;
  // ---- diagnostic non-zero ----
  unsigned long long* EpackD = (unsigned long long*)alloc((size_t)NB * 8);
  unsigned* seqD   = (unsigned*)alloc((size_t)n * 4);
  uint2*    skey2D = (uint2*)alloc((size_t)n * 8);
  unsigned* sidxD  = (unsigned*)alloc((size_t)n * 4);
  float*    xhD    = (float*)alloc((size_t)m * 4);
  float*    outD   = (float*)alloc(256);
  size_t offAll = off;

  if (offReal > ws_size) return;
  bool doDiag = (offAll <= ws_size);

  int gN = (n + BLK - 1) / BLK;              // 1024 for n=262144
  int tot = gN * BLK;
  int gS = NB / 1024;                        // 256 scan blocks

  hipMemsetAsync(ws, 0, doDiag ? zAll : zReal, stream);

  if (doDiag) {
    kD_hist<<<dim3(gN), dim3(BLK), 0, stream>>>(yt0, yp0, Hj, n, m, tot,
                                                recD, seqD, bitmapD);
    kD_scan<<<dim3(gS), dim3(BLK), 0, stream>>>(recD, pubD, EpackD);
    kD_scatter<<<dim3(gN), dim3(BLK), 0, stream>>>(yt0, yp0, n, seqD, EpackD,
                                                   skey2D, sidxD);
    kD_main<<<dim3(gN), dim3(BLK), 0, stream>>>(yt0, yp0, yp1, Hj, lv, n, m,
                                                bitmapD, EpackD, skey2D, sidxD,
                                                xhD, accumD, doneCntD, outD);
  }

  // real pipeline (R23, byte-identical)
  k_hist<<<dim3(gN), dim3(BLK), 0, stream>>>(yt0, yp0, Hj, n, m, tot,
                                             rec, seq, bitmap);
  k_scan<<<dim3(gS), dim3(BLK), 0, stream>>>(rec, pub, Epack);
  k_scatter<<<dim3(gN), dim3(BLK), 0, stream>>>(yt0, yp0, n, seq, Epack,
                                                skey2, sidx);
  k_main<<<dim3(gN), dim3(BLK), 0, stream>>>(yt0, yp0, yp1, Hj, lv, n, m,
                                             bitmap, Epack, skey2, sidx,
                                             xh, accum, doneCnt,
                                             (float*)d_out);
}

// Round 15
// 125.763 us; speedup vs baseline: 2.5368x; 2.5368x over previous
//
#include <hip/hip_runtime.h>
#include <math.h>

// Round 26: SCATTERED-ORDER streaming k_main. R25 attribution: k_main =
// 27.6us/iter (half the pipeline), FETCH 13MB/iter L2-miss traffic —
// original-order random gather chain (Epack + skey2/sidx walk) has combined
// random footprint > 4MB per-XCD L2 -> thrash every iteration (why cold==warm
// in R24 and R23's "L2-resident" fix failed: COMBINED footprint).
// Fix (R16-verified pattern @ lambda=1):
//   - k_scatter scatters ALL elements: skey2[pos]={key,e}, sidx[pos]=i|ev.
//     Only random read = Epack gather (2MB, L2-fits).
//   - k_main iterates SCATTERED p: skey2/sidx coalesced streams; b monotone
//     in p -> Epack reads sequential L1 hits; walk = wave's own neighborhood;
//     rank ~= p -> bitmap sequential; only ~3% yp1 gathers random.
// Per-element math/tie-break bit-identical (walk masks ev bit; self excluded).
// Pipeline: memset | k_hist | k_scan | k_scatter | k_main(+last-block final).

#define NB (1 << 18)             // linear time buckets, lambda = 1
#define BLK 256
#define M40 ((1ull << 40) - 1)

#define STORE_F32_A(p, v) __hip_atomic_store((p), (v), __ATOMIC_RELAXED, __HIP_MEMORY_SCOPE_AGENT)
#define STORE_U64_A(p, v) __hip_atomic_store((unsigned long long*)(p), (v), __ATOMIC_RELAXED, __HIP_MEMORY_SCOPE_AGENT)
#define LOAD_U64_A(p) __hip_atomic_load((const unsigned long long*)(p), __ATOMIC_RELAXED, __HIP_MEMORY_SCOPE_AGENT)
#define LOAD_F32_A(p) __hip_atomic_load((const float*)(p), __ATOMIC_RELAXED, __HIP_MEMORY_SCOPE_AGENT)
#define FADD_U32_A(p, v) __hip_atomic_fetch_add((p), (v), __ATOMIC_RELAXED, __HIP_MEMORY_SCOPE_AGENT)

__device__ __forceinline__ int lin_bucket(float t) {
  int b = (int)(t * 256.0f);     // exact (pow2 scale): strictly monotone
  if (b < 0) b = 0;
  if (b > NB - 1) b = NB - 1;
  return b;
}

// ---------------- D1: histogram + ticket + bitmap ----------------
__global__ void __launch_bounds__(BLK, 4)
k_hist(const float2* __restrict__ yt0, const float* __restrict__ yp0,
       const int* __restrict__ Hj, int n, int m, int tot,
       unsigned long long* __restrict__ rec, unsigned* __restrict__ seq,
       unsigned* __restrict__ bitmap) {
  int i = blockIdx.x * BLK + threadIdx.x;
  if (i < n) {
    float2 te = yt0[i];
    float e = expf(yp0[i]);
    int b = lin_bucket(te.x);
    unsigned long long qe = (unsigned long long)(e * 16777216.0f + 0.5f);
    if (qe > (1ull << 32)) qe = (1ull << 32);   // distribution safety clamp
    unsigned long long ret = atomicAdd(&rec[b], (1ull << 40) | qe);
    seq[i] = (unsigned)(ret >> 40);
  }
  for (int j = i; j < m; j += tot) {             // Hj rank bitmap
    int h = Hj[j];
    atomicOr(&bitmap[h >> 5], 1u << (h & 31));
  }
}

// ---------------- D2: single-pass suffix scan (decoupled lookback) -------
__global__ void __launch_bounds__(BLK, 4)
k_scan(const unsigned long long* __restrict__ rec,
       unsigned long long* __restrict__ pub,
       unsigned long long* __restrict__ Epack) {
  __shared__ unsigned su[BLK];
  __shared__ float    sf[BLK];
  const int t = threadIdx.x, g = blockIdx.x;

  unsigned cK[4]; float fK[4];
  unsigned runc = 0u; float runf = 0.f;
  #pragma unroll
  for (int k = 0; k < 4; ++k) {
    int b = NB - 1 - (g * 1024 + t * 4 + k);
    unsigned long long v = rec[b];
    cK[k] = (unsigned)(v >> 40);
    fK[k] = (float)((double)(v & M40) * (1.0 / 16777216.0));
    runc += cK[k]; runf += fK[k];
  }
  su[t] = runc; sf[t] = runf;
  __syncthreads();
  for (int off2 = 1; off2 < BLK; off2 <<= 1) {   // inclusive Hillis-Steele
    unsigned uc = (t >= off2) ? su[t - off2] : 0u;
    float    uf = (t >= off2) ? sf[t - off2] : 0.f;
    __syncthreads();
    su[t] += uc; sf[t] += uf;
    __syncthreads();
  }
  if (t == BLK - 1)
    STORE_U64_A(&pub[g], (1ull << 63) |
                ((unsigned long long)(su[t] & 0x7FFFFFFFu) << 32) |
                (unsigned long long)__float_as_uint(sf[t]));
  unsigned thrC = (t > 0) ? su[t - 1] : 0u;
  float    thrF = (t > 0) ? sf[t - 1] : 0.f;
  __syncthreads();

  unsigned pc = 0u; float pf = 0.f;
  for (int j = t; j < g; j += BLK) {
    unsigned long long v;
    int guard = 0;
    while (!(((v = LOAD_U64_A(&pub[j])) >> 63) & 1ull)) {
      __builtin_amdgcn_s_sleep(1);
      if (++guard > 5000000) break;              // failsafe: never hang
    }
    pc += (unsigned)((v >> 32) & 0x7FFFFFFFu);
    pf += __uint_as_float((unsigned)v);
  }
  su[t] = pc; sf[t] = pf;
  __syncthreads();
  for (int s = BLK / 2; s > 0; s >>= 1) {
    if (t < s) { su[t] += su[t + s]; sf[t] += sf[t + s]; }
    __syncthreads();
  }
  const unsigned baseC = su[0]; const float baseF = sf[0];
  __syncthreads();

  unsigned preC = 0u; float preF = 0.f;
  #pragma unroll
  for (int k = 0; k < 4; ++k) {
    int b = NB - 1 - (g * 1024 + t * 4 + k);
    unsigned sfxC = baseC + thrC + preC;          // S[b] (elems in buckets > b)
    float    sfxF = baseF + thrF + preF;          // crossF[b]
    Epack[b] = ((unsigned long long)__float_as_uint(sfxF) << 32) | sfxC;
    preC += cK[k]; preF += fK[k];
  }
}

// ---------------- D3: scatter ALL elements ----------------
__global__ void __launch_bounds__(BLK, 4)
k_scatter(const float2* __restrict__ yt0, const float* __restrict__ yp0, int n,
          const unsigned* __restrict__ seq,
          const unsigned long long* __restrict__ Epack,
          uint2* __restrict__ skey2, unsigned* __restrict__ sidx) {
  int i = blockIdx.x * BLK + threadIdx.x;
  if (i >= n) return;
  float2 te = yt0[i];
  unsigned key = __float_as_uint(te.x);
  unsigned ev = (te.y != 0.f) ? 0x80000000u : 0u;
  int b = lin_bucket(te.x);
  unsigned start = ((const unsigned*)Epack)[2u * (unsigned)b];  // only random read
  float e = expf(yp0[i]);                         // bitwise == k_hist's e
  unsigned pos = start + seq[i];
  uint2 v; v.x = key; v.y = __float_as_uint(e);
  skey2[pos] = v;                                 // random write, 3MB L2-merged
  sidx[pos] = (unsigned)i | ev;
}

// ---------------- D4: STREAMING main (scattered order) + final -----------
__global__ void __launch_bounds__(BLK, 4)
k_main(const float* __restrict__ yp1, const int* __restrict__ Hj,
       const float* __restrict__ lv, int n, int m,
       const unsigned* __restrict__ bitmap,
       const unsigned long long* __restrict__ Epack,
       const uint2* __restrict__ skey2, const unsigned* __restrict__ sidx,
       float* __restrict__ xh, double* __restrict__ accum,
       unsigned* __restrict__ doneCnt, float* __restrict__ out) {
  __shared__ double sd[BLK];
  __shared__ float  wt[4];
  __shared__ int    lastFlag;
  const int t = threadIdx.x;
  int p = blockIdx.x * BLK + t;
  double contrib = 0.0;
  if (p < n) {
    uint2 kv = skey2[p];                          // coalesced stream
    unsigned key = kv.x;
    float e = __uint_as_float(kv.y);
    unsigned sidv = sidx[p];                      // coalesced stream
    unsigned idx = sidv & 0x7FFFFFFFu;
    bool evb = (sidv >> 31) != 0u;
    int b = lin_bucket(__uint_as_float(key));
    unsigned long long ep = Epack[b];             // sequential-ish: L1 hit
    unsigned start = (unsigned)ep;
    float cross = __uint_as_float((unsigned)(ep >> 32));
    unsigned end = (b > 0) ? ((const unsigned*)Epack)[2u * (unsigned)(b - 1)]
                           : (unsigned)n;
    if (end > (unsigned)n) end = (unsigned)n;     // defensive clamps
    if (start > end) start = end;
    float wsum = 0.f;
    unsigned wcnt = 0u;
    if (end - start > 1u) {                       // walk = own neighborhood
      for (unsigned q = start; q < end; ++q) {
        uint2 v = skey2[q];
        if (v.x > key) { wsum += __uint_as_float(v.y); wcnt++; }
        else if (v.x == key && (sidx[q] & 0x7FFFFFFFu) < idx) {
          wsum += __uint_as_float(v.y); wcnt++;
        }
      }
    }
    float denom = cross + wsum + e;
    int rank = (int)(start + wcnt);
    if (evb) contrib = (double)logf(denom / e);
    if ((bitmap[rank >> 5] >> (rank & 31)) & 1u) {   // rank~p: sequential
      int lo = 0, hi = m;
      while (lo < hi) { int mid = (lo + hi) >> 1; if (Hj[mid] < rank) lo = mid + 1; else hi = mid; }
      if (lo < m && Hj[lo] == rank) {
        float xb1 = yp1[idx];                     // rare random gather (~3%)
        for (int j = lo; j < m && Hj[j] == rank; ++j) STORE_F32_A(&xh[j], xb1);
      }
    }
  }
  sd[t] = contrib;
  __syncthreads();
  for (int s = 128; s > 0; s >>= 1) { if (t < s) sd[t] += sd[t + s]; __syncthreads(); }
  // last __syncthreads drained every wave's stores (incl. sc1 xh writes)
  if (t == 0) {
    double old = atomicAdd(accum, sd[0]);
    unsigned long long ob = __double_as_longlong(old);
    asm volatile("" :: "v"(ob));                  // force accum RMW completion
    unsigned r = FADD_U32_A(doneCnt, 1u);
    lastFlag = (r == gridDim.x - 1u) ? 1 : 0;
  }
  __syncthreads();
  if (lastFlag == 0) return;

  // ---- P6 (last block only): cost2 + combine ----
  {
    int lane = t & 63;
    int w = t >> 6;
    double acc = 0.0;
    float carry = 0.f;
    int passes = (m + 2047) / 2048;               // 4 for m=8192
    for (int pss = passes - 1; pss >= 0; --pss) {
      int base = pss * 2048 + t * 8;
      float x[8], eb[8];
      float c = 0.f;
      #pragma unroll
      for (int k = 0; k < 8; ++k) {
        int j = base + k;
        x[k] = (j < m) ? LOAD_F32_A(&xh[j]) : 0.f;
        eb[k] = (j < m) ? expf(-x[k]) : 0.f;
        c += eb[k];
      }
      float s = c;
      #pragma unroll
      for (int d = 1; d < 64; d <<= 1) {
        float o = __shfl_down(s, d, 64);
        if (lane + d < 64) s += o;
      }
      float wtot = __shfl(s, 0, 64);
      if (lane == 0) wt[w] = wtot;
      __syncthreads();
      float after = 0.f, ptot = 0.f;
      #pragma unroll
      for (int w2 = 0; w2 < 4; ++w2) { ptot += wt[w2]; if (w2 > w) after += wt[w2]; }
      float S = (s - c) + after + carry;
      #pragma unroll
      for (int k = 7; k >= 0; --k) {
        int j = base + k;
        S += eb[k];
        if (j < m) acc += (double)(expf(x[k]) * S);
      }
      __syncthreads();
      carry += ptot;
    }
    sd[t] = acc;
    __syncthreads();
    for (int s2 = 128; s2 > 0; s2 >>= 1) { if (t < s2) sd[t] += sd[t + s2]; __syncthreads(); }
    if (t == 0) {
      double T = (double)m * (double)(m + 1) * 0.5;
      double cost2 = T - sd[0];
      float lv0 = lv[0], lv1 = lv[1];
      float prec1 = fminf(expf(-lv1), 1.0f);
      double av = __longlong_as_double((long long)LOAD_U64_A(accum));
      double loss = av + (double)n * (double)lv0 + (double)prec1 * cost2 + (double)lv1;
      out[0] = (float)loss;
    }
  }
}

extern "C" void kernel_launch(void* const* d_in, const int* in_sizes, int n_in,
                              void* d_out, int out_size, void* d_ws, size_t ws_size,
                              hipStream_t stream) {
  (void)n_in; (void)out_size;
  const float2* yt0 = (const float2*)d_in[0];
  const float*  yp0 = (const float*)d_in[2];
  const float*  yp1 = (const float*)d_in[3];
  const int*    Hj  = (const int*)d_in[4];
  const float*  lv  = (const float*)d_in[5];
  int n = in_sizes[0] / 2;   // y_true0 is [N,2]
  int m = in_sizes[4];

  char* ws = (char*)d_ws;
  size_t off = 0;
  auto alloc = [&](size_t bytes) -> void* {
    void* p = ws + off;
    off += (bytes + 255) & ~(size_t)255;
    return p;
  };
  double*   accum   = (double*)alloc(128);                         // zeroed
  unsigned* doneCnt = (unsigned*)alloc(128);                       // zeroed
  size_t nbm = ((size_t)(n + 31) / 32) * 4;                        // 32 KB
  unsigned* bitmap  = (unsigned*)alloc(nbm);                       // zeroed
  unsigned long long* pub = (unsigned long long*)alloc((NB / 1024) * 8); // zeroed
  unsigned long long* rec = (unsigned long long*)alloc((size_t)NB * 8);  // 2MB zeroed
  size_t zbytes = off;                     // everything above must start zero
  unsigned long long* Epack = (unsigned long long*)alloc((size_t)NB * 8); // 2MB
  unsigned* seq   = (unsigned*)alloc((size_t)n * 4);               // 1MB
  uint2*    skey2 = (uint2*)alloc((size_t)n * 8);                  // 2MB
  unsigned* sidx  = (unsigned*)alloc((size_t)n * 4);               // 1MB
  float*    xh    = (float*)alloc((size_t)m * 4);
  if (off > ws_size) return;

  hipMemsetAsync(ws, 0, zbytes, stream);

  int gN = (n + BLK - 1) / BLK;              // 1024 for n=262144
  int tot = gN * BLK;
  int gS = NB / 1024;                        // 256 scan blocks
  k_hist<<<dim3(gN), dim3(BLK), 0, stream>>>(yt0, yp0, Hj, n, m, tot,
                                             rec, seq, bitmap);
  k_scan<<<dim3(gS), dim3(BLK), 0, stream>>>(rec, pub, Epack);
  k_scatter<<<dim3(gN), dim3(BLK), 0, stream>>>(yt0, yp0, n, seq, Epack,
                                                skey2, sidx);
  k_main<<<dim3(gN), dim3(BLK), 0, stream>>>(yp1, Hj, lv, n, m,
                                             bitmap, Epack, skey2, sidx,
                                             xh, accum, doneCnt,
                                             (float*)d_out);
}